// Round 4
// baseline (517.384 us; speedup 1.0000x reference)
//
#include <hip/hip_runtime.h>
#include <hip/hip_bf16.h>

// ---------------- types ----------------
typedef __attribute__((ext_vector_type(8))) short s16x8;   // 8 bf16 in 4 VGPRs
typedef __attribute__((ext_vector_type(4))) float f32x4;

// B=4, C=256, H=W=160, padded spatial 162, S dims 161, N=512, REID=128

__device__ __forceinline__ void async_ld16(const void* g, void* l) {
  __builtin_amdgcn_global_load_lds(
      (const __attribute__((address_space(1))) void*)g,
      (__attribute__((address_space(3))) void*)l, 16, 0, 0);
}

// ---------------- 0. zero only the pad borders of xpad and f1 ----------------
__global__ __launch_bounds__(256) void zero_borders(__hip_bfloat16* __restrict__ xpad,
                                                    __hip_bfloat16* __restrict__ f1) {
  int bi = blockIdx.x;
  int buf = bi / 2576; int rem = bi - buf * 2576;
  int b = rem / 644;   int e = rem - b * 644;
  int y, x;
  if (e < 162)      { y = 0;           x = e; }
  else if (e < 324) { y = 161;         x = e - 162; }
  else if (e < 484) { y = e - 324 + 1; x = 0; }
  else              { y = e - 484 + 1; x = 161; }
  __hip_bfloat16* p = (buf ? f1 : xpad) + (((size_t)b * 162 + y) * 162 + x) * 256 + threadIdx.x;
  *p = __float2bfloat16(0.f);
}

// ---------------- 1. NCHW fp32 -> padded NHWC bf16 ----------------
__global__ __launch_bounds__(256) void nchw2nhwc(const float* __restrict__ x,
                                                 __hip_bfloat16* __restrict__ xpad) {
  __shared__ float tile[32][33];
  int blk = blockIdx.x;
  int xt = blk % 5;
  int ct = (blk / 5) & 7;
  int by = blk / 40;
  int b = by / 160, y = by - (by / 160) * 160;
  int tx = threadIdx.x, ty = threadIdx.y;
  const float* src = x + (((size_t)(b * 256 + ct * 32)) * 160 + y) * 160 + xt * 32 + tx;
#pragma unroll
  for (int k = 0; k < 4; k++) tile[ty * 4 + k][tx] = src[(size_t)(ty * 4 + k) * 25600];
  __syncthreads();
  __hip_bfloat16* dst = xpad + (((size_t)(b * 162 + y + 1)) * 162 + (xt * 32 + 1)) * 256 + ct * 32 + tx;
#pragma unroll
  for (int k = 0; k < 4; k++) {
    int xx = ty * 4 + k;
    dst[(size_t)xx * 256] = __float2bfloat16(tile[tx][xx]);
  }
}

// ---------------- 2. weight pack: (L,Cout,Cin,3,3) fp32 -> [L][tap][co][ci] bf16 ----------------
__global__ __launch_bounds__(256) void pack_w(const float* __restrict__ cw,
                                              __hip_bfloat16* __restrict__ wpk) {
  int t = blockIdx.x * 256 + threadIdx.x;
  int ci = t & 255, co = (t >> 8) & 255, rest = t >> 16;
  int tap = rest % 9, l = rest / 9;
  int dy = tap / 3, dx = tap - dy * 3;
  float v = cw[((((size_t)l * 256 + co) * 256 + ci) * 3 + dy) * 3 + dx];
  wpk[(((size_t)l * 9 + tap) * 256 + co) * 256 + ci] = __float2bfloat16(v);
}

// ---------------- 3. fold conv-bias + BN into per-channel alpha/beta ----------------
__global__ void prep_bn(const float* __restrict__ cb, const float* __restrict__ g,
                        const float* __restrict__ bt, const float* __restrict__ mn,
                        const float* __restrict__ vr, float* __restrict__ ab) {
  int t = blockIdx.x * 256 + threadIdx.x;  // 512
  float a = g[t] / sqrtf(vr[t] + 1e-5f);
  ab[t] = a;
  ab[512 + t] = (cb[t] - mn[t]) * a + bt[t];
}

// ---------------- 3b. transpose MLP weights for coalesced reads ----------------
__global__ __launch_bounds__(256) void pack_mlp(const float* __restrict__ w1,
                                                const float* __restrict__ w2,
                                                float* __restrict__ w1t,
                                                float* __restrict__ w2t) {
  int t = blockIdx.x * 256 + threadIdx.x;
  if (t < 32768) {
    int h = t >> 8, k = t & 255;
    w1t[k * 128 + h] = w1[h * 256 + k];
  } else {
    int u = t - 32768;
    int r = u >> 7, k = u & 127;
    w2t[k * 128 + r] = w2[r * 128 + k];
  }
}

// ---------------- 4. conv3x3 + BN + ReLU, implicit GEMM, counted-vmcnt ring pipeline (T3+T4+T5) --
// BM=128, BN=128, BK=32; 4 waves 64x64; ring of 4 LDS buffers; prefetch depth 3;
// one raw s_barrier per K-step, s_waitcnt vmcnt(8) counted (never 0 in steady state).
// K-window swizzle: phys slot s = lq ^ ((row>>1)&3) via pre-swizzled global source (rule #21).
__global__ __launch_bounds__(256, 2) void conv_bn_relu(
    const __hip_bfloat16* __restrict__ inp, __hip_bfloat16* __restrict__ outp,
    const __hip_bfloat16* __restrict__ wpk,  // [9][256][256] (tap, co, ci)
    const float* __restrict__ alpha, const float* __restrict__ beff) {
  __shared__ __align__(16) short As[4 * 4096];   // 4 ring bufs x 8 KB
  __shared__ __align__(16) short Bs[4 * 4096];
  const int t = threadIdx.x;
  // T1: bijective XCD swizzle (grid 1600 = 8*200)
  const int logical = ((blockIdx.x & 7) * 200) + (blockIdx.x >> 3);
  const int mtile = logical >> 1;
  const int ntile = logical & 1;
  const int l = t & 63;
  const int wv = t >> 6;
  const int lr = l & 15, lq = l >> 4;
  const int wm = wv >> 1, wn = wv & 1;
  const int co0 = ntile << 7;

  // staging: thread t, issue i in {0,1}: physical 16B slot p = i*256 + t (linear LDS dest).
  // logical row r = i*64 + (t>>2); source k-chunk = (t&3) ^ ((r>>1)&3) = (t&3) ^ ((t>>3)&3).
  const int koff = (((t & 3) ^ ((t >> 3) & 3)) << 3);  // shorts
  const short* inS = (const short*)inp;
  const short* wS = (const short*)wpk;
  long abase0, abase1;
  {
    int p0 = mtile * 128 + (t >> 2);
    int b0 = p0 / 25600; int r0 = p0 - b0 * 25600; int y0 = r0 / 160; int x0 = r0 - y0 * 160;
    abase0 = (((long)b0 * 162 + y0) * 162 + x0) * 256 + koff;
    int p1 = p0 + 64;
    int b1 = p1 / 25600; int r1 = p1 - b1 * 25600; int y1 = r1 / 160; int x1 = r1 - y1 * 160;
    abase1 = (((long)b1 * 162 + y1) * 162 + x1) * 256 + koff;
  }
  const long bbase0 = ((long)(co0 + (t >> 2))) * 256 + koff;
  const long bbase1 = bbase0 + 64 * 256;

  // u = tap*8 + kc; 72 K-steps of BK=32
  auto stage = [&](int u) {
    const int tap = u >> 3, kc = u & 7;
    const int dy = tap / 3, dx = tap - dy * 3;
    const long aoff = ((long)(dy * 162 + dx)) * 256 + kc * 32;
    const long boff = (long)tap * 65536 + kc * 32;
    short* ad = As + (u & 3) * 4096 + t * 8;
    short* bd = Bs + (u & 3) * 4096 + t * 8;
    async_ld16(inS + abase0 + aoff, ad);
    async_ld16(inS + abase1 + aoff, ad + 2048);
    async_ld16(wS + bbase0 + boff, bd);
    async_ld16(wS + bbase1 + boff, bd + 2048);
  };

  f32x4 acc[4][4];
#pragma unroll
  for (int i = 0; i < 4; i++)
#pragma unroll
    for (int j = 0; j < 4; j++) acc[i][j] = (f32x4){0.f, 0.f, 0.f, 0.f};

  const int psA = ((lq ^ ((lr >> 1) & 3)) << 3);  // swizzled k-chunk (shorts), row-dependent part folded

  auto compute = [&](int u) {
    const short* Ab = As + (u & 3) * 4096;
    const short* Bb = Bs + (u & 3) * 4096;
    s16x8 av[4], bv[4];
#pragma unroll
    for (int mi = 0; mi < 4; ++mi)
      av[mi] = *(const s16x8*)&Ab[(wm * 64 + mi * 16 + lr) * 32 + psA];
#pragma unroll
    for (int ni = 0; ni < 4; ++ni)
      bv[ni] = *(const s16x8*)&Bb[(wn * 64 + ni * 16 + lr) * 32 + psA];
    __builtin_amdgcn_s_setprio(1);
#pragma unroll
    for (int mi = 0; mi < 4; ++mi)
#pragma unroll
      for (int ni = 0; ni < 4; ++ni)
        acc[mi][ni] = __builtin_amdgcn_mfma_f32_16x16x32_bf16(av[mi], bv[ni], acc[mi][ni], 0, 0, 0);
    __builtin_amdgcn_s_setprio(0);
  };

  stage(0); stage(1); stage(2);  // 12 loads in flight
#pragma unroll 1
  for (int u = 0; u < 69; ++u) {
    asm volatile("s_waitcnt vmcnt(8)" ::: "memory");  // stage(u) landed; u+1,u+2 stay in flight
    __builtin_amdgcn_s_barrier();                     // all waves: buf[u&3] ready, buf[(u-1)&3] free
    __builtin_amdgcn_sched_barrier(0);
    stage(u + 3);                                     // overwrite buf[(u-1)&3]
    compute(u);
  }
  asm volatile("s_waitcnt vmcnt(8)" ::: "memory");
  __builtin_amdgcn_s_barrier();
  __builtin_amdgcn_sched_barrier(0);
  compute(69);
  asm volatile("s_waitcnt vmcnt(4)" ::: "memory");
  __builtin_amdgcn_s_barrier();
  __builtin_amdgcn_sched_barrier(0);
  compute(70);
  asm volatile("s_waitcnt vmcnt(0)" ::: "memory");
  __builtin_amdgcn_s_barrier();
  __builtin_amdgcn_sched_barrier(0);
  compute(71);

  // epilogue: y = relu(acc*alpha + beff) -> bf16, padded NHWC
  float al[4], be_[4];
#pragma unroll
  for (int ni = 0; ni < 4; ++ni) {
    int co = co0 + wn * 64 + ni * 16 + lr;
    al[ni] = alpha[co];
    be_[ni] = beff[co];
  }
#pragma unroll
  for (int mi = 0; mi < 4; ++mi) {
    int prow = mtile * 128 + wm * 64 + mi * 16 + lq * 4;
#pragma unroll
    for (int j = 0; j < 4; ++j) {
      int p = prow + j;
      int b = p / 25600; int r = p - b * 25600; int y = r / 160; int x = r - y * 160;
      long ob = (((long)b * 162 + (y + 1)) * 162 + (x + 1)) * 256 + co0 + wn * 64;
#pragma unroll
      for (int ni = 0; ni < 4; ++ni) {
        float v = acc[mi][ni][j] * al[ni] + be_[ni];
        outp[ob + ni * 16 + lr] = __float2bfloat16(fmaxf(v, 0.f));
      }
    }
  }
}

// ---------------- 5. cumsum along W: bf16 f -> fp32 S, channel-pair vectorized ----------------
__global__ __launch_bounds__(256) void cumsum_w(const __hip_bfloat16* __restrict__ f2,
                                                float* __restrict__ S) {
  int row = blockIdx.x * 2 + (threadIdx.x >> 7);   // 0..639
  int b = row / 160, y = row - (row / 160) * 160;
  int cp = threadIdx.x & 127;                      // channel pair index
  const unsigned* src =
      (const unsigned*)((const short*)f2 + (((size_t)b * 162 + y + 1) * 162 + 1) * 256) + cp;
  float2* dst = (float2*)(S + (((size_t)b * 161 + y + 1) * 161) * 256) + cp;
  dst[0] = float2{0.f, 0.f};
  float r0 = 0.f, r1 = 0.f;
  for (int x4 = 0; x4 < 160; x4 += 4) {
    unsigned v[4];
#pragma unroll
    for (int k = 0; k < 4; k++) v[k] = src[(size_t)(x4 + k) * 128];
#pragma unroll
    for (int k = 0; k < 4; k++) {
      r0 += __uint_as_float((v[k] & 0xffffu) << 16);
      r1 += __uint_as_float(v[k] & 0xffff0000u);
      dst[(size_t)(x4 + k + 1) * 128] = float2{r0, r1};
    }
  }
}

// ---------------- 6. cumsum along H in place ----------------
__global__ __launch_bounds__(256) void cumsum_h(float* __restrict__ S) {
  int bi = blockIdx.x;  // 4*161
  int b = bi / 161, q = bi - (bi / 161) * 161;
  int c = threadIdx.x;
  float* col = S + (((size_t)b * 161) * 161 + q) * 256 + c;
  const size_t ys = (size_t)161 * 256;
  col[0] = 0.f;
  float run = 0.f;
  for (int y0 = 1; y0 <= 160; y0 += 8) {
    float v[8];
#pragma unroll
    for (int k = 0; k < 8; k++) v[k] = col[(size_t)(y0 + k) * ys];
#pragma unroll
    for (int k = 0; k < 8; k++) { run += v[k]; col[(size_t)(y0 + k) * ys] = run; }
  }
}

// ---------------- 7. ROI adaptive 7x7 pool + global avg via integral image ----------------
__global__ __launch_bounds__(256) void roi_pool(const float* __restrict__ S,
                                                const float* __restrict__ bbox,
                                                float* __restrict__ pooled,
                                                int* __restrict__ valid) {
  int bn = blockIdx.x;  // 0..2047
  int b = bn >> 9;
  int c = threadIdx.x;
  float bx1 = bbox[bn * 4 + 0], by1 = bbox[bn * 4 + 1];
  float bx2 = bbox[bn * 4 + 2], by2 = bbox[bn * 4 + 3];
  int x1 = min(max((int)floorf(bx1 * 160.f), 0), 160);
  int y1 = min(max((int)floorf(by1 * 160.f), 0), 160);
  int x2 = min(max((int)floorf(bx2 * 160.f), 0), 160);
  int y2 = min(max((int)floorf(by2 * 160.f), 0), 160);
  int vld = (x2 > x1 && y2 > y1) ? 1 : 0;
  int hl = max(y2 - y1, 1), wl = max(x2 - x1, 1);
  int hs[7], he[7], ws_[7], we_[7];
  float rh[7], rw[7];
#pragma unroll
  for (int i = 0; i < 7; i++) {
    hs[i] = y1 + (i * hl) / 7;
    he[i] = y1 + ((i + 1) * hl + 6) / 7;
    rh[i] = 1.f / (float)(he[i] - hs[i]);
    ws_[i] = x1 + (i * wl) / 7;
    we_[i] = x1 + ((i + 1) * wl + 6) / 7;
    rw[i] = 1.f / (float)(we_[i] - ws_[i]);
  }
  const float* Sb = S + (size_t)b * 161 * 161 * 256 + c;
  float acc = 0.f;
#pragma unroll
  for (int i = 0; i < 7; i++) {
    const float* rE = Sb + (size_t)he[i] * (161 * 256);
    const float* rS = Sb + (size_t)hs[i] * (161 * 256);
#pragma unroll
    for (int j = 0; j < 7; j++) {
      size_t qe = (size_t)we_[j] * 256, qs = (size_t)ws_[j] * 256;
      float s = rE[qe] - rS[qe] - rE[qs] + rS[qs];
      acc += s * (rh[i] * rw[j]);
    }
  }
  pooled[(size_t)bn * 256 + c] = acc * (1.f / 49.f);
  if (c == 0) valid[bn] = vld;
}

// ---------------- 8. MLP (256->128 relu ->128) + mask + L2 normalize ----------------
__global__ __launch_bounds__(128) void mlp_norm(const float* __restrict__ pooled,
                                                const int* __restrict__ valid,
                                                const float* __restrict__ w1t,
                                                const float* __restrict__ b1,
                                                const float* __restrict__ w2t,
                                                const float* __restrict__ b2,
                                                float* __restrict__ out) {
  int bn = blockIdx.x;
  int t = threadIdx.x;
  __shared__ float pl[256];
  __shared__ float hh[128];
  __shared__ float red[2];
  pl[t] = pooled[(size_t)bn * 256 + t];
  pl[t + 128] = pooled[(size_t)bn * 256 + 128 + t];
  __syncthreads();
  float a = b1[t];
#pragma unroll 8
  for (int k = 0; k < 256; k++) a += w1t[k * 128 + t] * pl[k];
  hh[t] = fmaxf(a, 0.f);
  __syncthreads();
  float f = b2[t];
#pragma unroll 8
  for (int k = 0; k < 128; k++) f += w2t[k * 128 + t] * hh[k];
  if (!valid[bn]) f = 0.f;
  float ss = f * f;
#pragma unroll
  for (int off = 32; off > 0; off >>= 1) ss += __shfl_xor(ss, off);
  if ((t & 63) == 0) red[t >> 6] = ss;
  __syncthreads();
  float nrm = fmaxf(sqrtf(red[0] + red[1]), 1e-12f);
  out[(size_t)bn * 128 + t] = f / nrm;
}

// ---------------- launch ----------------
extern "C" void kernel_launch(void* const* d_in, const int* in_sizes, int n_in,
                              void* d_out, int out_size, void* d_ws, size_t ws_size,
                              hipStream_t stream) {
  const float* x = (const float*)d_in[0];
  const float* bboxes = (const float*)d_in[1];
  const float* conv_w = (const float*)d_in[2];
  const float* conv_b = (const float*)d_in[3];
  const float* bn_g = (const float*)d_in[4];
  const float* bn_b = (const float*)d_in[5];
  const float* bn_m = (const float*)d_in[6];
  const float* bn_v = (const float*)d_in[7];
  const float* w1 = (const float*)d_in[8];
  const float* b1 = (const float*)d_in[9];
  const float* w2 = (const float*)d_in[10];
  const float* b2 = (const float*)d_in[11];

  char* ws = (char*)d_ws;
  const size_t PADB = (size_t)4 * 162 * 162 * 256 * 2;   // 53,747,712 B
  const size_t WPKB = (size_t)2 * 9 * 256 * 256 * 2;     // 2,359,296 B
  const size_t SB = (size_t)4 * 161 * 161 * 256 * 4;     // 106,172,416 B
  const size_t PLB = (size_t)4 * 512 * 256 * 4;          // pooled 2 MB

  __hip_bfloat16* xpad = (__hip_bfloat16*)(ws);
  __hip_bfloat16* f1 = (__hip_bfloat16*)(ws + PADB);
  __hip_bfloat16* wpk = (__hip_bfloat16*)(ws + 2 * PADB);
  float* abuf = (float*)(ws + 2 * PADB + WPKB);
  float* S = (float*)(ws + 2 * PADB + WPKB + 4096);
  float* pooled = (float*)(ws + 2 * PADB + WPKB + 4096 + SB);
  int* valid = (int*)(ws + 2 * PADB + WPKB + 4096 + SB + PLB);
  float* w1t = (float*)(ws + 2 * PADB + WPKB + 4096 + SB + PLB + 8192);
  float* w2t = w1t + 32768;

  zero_borders<<<5152, 256, 0, stream>>>(xpad, f1);
  nchw2nhwc<<<25600, dim3(32, 8), 0, stream>>>(x, xpad);
  pack_w<<<4608, 256, 0, stream>>>(conv_w, wpk);
  prep_bn<<<2, 256, 0, stream>>>(conv_b, bn_g, bn_b, bn_m, bn_v, abuf);
  pack_mlp<<<192, 256, 0, stream>>>(w1, w2, w1t, w2t);

  conv_bn_relu<<<1600, 256, 0, stream>>>(xpad, f1, wpk, abuf, abuf + 512);
  conv_bn_relu<<<1600, 256, 0, stream>>>(f1, xpad, wpk + (size_t)9 * 256 * 256, abuf + 256, abuf + 768);

  cumsum_w<<<320, 256, 0, stream>>>(xpad, S);
  cumsum_h<<<644, 256, 0, stream>>>(S);
  roi_pool<<<2048, 256, 0, stream>>>(S, bboxes, pooled, valid);
  mlp_norm<<<2048, 128, 0, stream>>>(pooled, valid, w1t, b1, w2t, b2, (float*)d_out);
}

// Round 5
// 403.944 us; speedup vs baseline: 1.2808x; 1.2808x over previous
//
#include <hip/hip_runtime.h>
#include <hip/hip_bf16.h>

// ---------------- types ----------------
typedef __attribute__((ext_vector_type(8))) short s16x8;   // 8 bf16 in 4 VGPRs
typedef __attribute__((ext_vector_type(4))) float f32x4;

// B=4, C=256, H=W=160, padded spatial 162, S dims 161, N=512, REID=128

__device__ __forceinline__ void async_ld16(const void* g, void* l) {
  __builtin_amdgcn_global_load_lds(
      (const __attribute__((address_space(1))) void*)g,
      (__attribute__((address_space(3))) void*)l, 16, 0, 0);
}

// ---------------- 0. zero only the pad borders of xpad and f1 ----------------
__global__ __launch_bounds__(256) void zero_borders(__hip_bfloat16* __restrict__ xpad,
                                                    __hip_bfloat16* __restrict__ f1) {
  int bi = blockIdx.x;
  int buf = bi / 2576; int rem = bi - buf * 2576;
  int b = rem / 644;   int e = rem - b * 644;
  int y, x;
  if (e < 162)      { y = 0;           x = e; }
  else if (e < 324) { y = 161;         x = e - 162; }
  else if (e < 484) { y = e - 324 + 1; x = 0; }
  else              { y = e - 484 + 1; x = 161; }
  __hip_bfloat16* p = (buf ? f1 : xpad) + (((size_t)b * 162 + y) * 162 + x) * 256 + threadIdx.x;
  *p = __float2bfloat16(0.f);
}

// ---------------- 1. NCHW fp32 -> padded NHWC bf16 ----------------
__global__ __launch_bounds__(256) void nchw2nhwc(const float* __restrict__ x,
                                                 __hip_bfloat16* __restrict__ xpad) {
  __shared__ float tile[32][33];
  int blk = blockIdx.x;
  int xt = blk % 5;
  int ct = (blk / 5) & 7;
  int by = blk / 40;
  int b = by / 160, y = by - (by / 160) * 160;
  int tx = threadIdx.x, ty = threadIdx.y;
  const float* src = x + (((size_t)(b * 256 + ct * 32)) * 160 + y) * 160 + xt * 32 + tx;
#pragma unroll
  for (int k = 0; k < 4; k++) tile[ty * 4 + k][tx] = src[(size_t)(ty * 4 + k) * 25600];
  __syncthreads();
  __hip_bfloat16* dst = xpad + (((size_t)(b * 162 + y + 1)) * 162 + (xt * 32 + 1)) * 256 + ct * 32 + tx;
#pragma unroll
  for (int k = 0; k < 4; k++) {
    int xx = ty * 4 + k;
    dst[(size_t)xx * 256] = __float2bfloat16(tile[tx][xx]);
  }
}

// ---------------- 2. weight pack: (L,Cout,Cin,3,3) fp32 -> [L][tap][co][ci] bf16 ----------------
__global__ __launch_bounds__(256) void pack_w(const float* __restrict__ cw,
                                              __hip_bfloat16* __restrict__ wpk) {
  int t = blockIdx.x * 256 + threadIdx.x;
  int ci = t & 255, co = (t >> 8) & 255, rest = t >> 16;
  int tap = rest % 9, l = rest / 9;
  int dy = tap / 3, dx = tap - dy * 3;
  float v = cw[((((size_t)l * 256 + co) * 256 + ci) * 3 + dy) * 3 + dx];
  wpk[(((size_t)l * 9 + tap) * 256 + co) * 256 + ci] = __float2bfloat16(v);
}

// ---------------- 3. fold conv-bias + BN into per-channel alpha/beta ----------------
__global__ void prep_bn(const float* __restrict__ cb, const float* __restrict__ g,
                        const float* __restrict__ bt, const float* __restrict__ mn,
                        const float* __restrict__ vr, float* __restrict__ ab) {
  int t = blockIdx.x * 256 + threadIdx.x;  // 512
  float a = g[t] / sqrtf(vr[t] + 1e-5f);
  ab[t] = a;
  ab[512 + t] = (cb[t] - mn[t]) * a + bt[t];
}

// ---------------- 3b. transpose MLP weights for coalesced reads ----------------
__global__ __launch_bounds__(256) void pack_mlp(const float* __restrict__ w1,
                                                const float* __restrict__ w2,
                                                float* __restrict__ w1t,
                                                float* __restrict__ w2t) {
  int t = blockIdx.x * 256 + threadIdx.x;
  if (t < 32768) {
    int h = t >> 8, k = t & 255;
    w1t[k * 128 + h] = w1[h * 256 + k];
  } else {
    int u = t - 32768;
    int r = u >> 7, k = u & 127;
    w2t[k * 128 + r] = w2[r * 128 + k];
  }
}

// ---------------- 4. conv3x3 + BN + ReLU, implicit GEMM (bf16 MFMA) ----------------
// BM=128, BN=256 (full N), BK=64; 4 waves, wave-tile 64x128 (4x8 frags of 16x16x32).
// 2-barrier K-step (proven structure); 64 MFMA per wave per step amortizes the drain.
// LDS linear, XOR-swizzled via pre-swizzled global source (rule #21); T1 XCD swizzle.
__global__ __launch_bounds__(256, 2) void conv_bn_relu(
    const __hip_bfloat16* __restrict__ inp, __hip_bfloat16* __restrict__ outp,
    const __hip_bfloat16* __restrict__ wpk,  // [9][256][256] (tap, co, ci)
    const float* __restrict__ alpha, const float* __restrict__ beff) {
  __shared__ __align__(16) short As[128 * 64];   // 16 KB
  __shared__ __align__(16) short Bs[256 * 64];   // 32 KB
  const int t = threadIdx.x;
  // T1: bijective XCD swizzle (grid 800 = 8*100)
  const int mtile = ((blockIdx.x & 7) * 100) + (blockIdx.x >> 3);  // 0..799
  const int l = t & 63;
  const int wv = t >> 6;
  const int lr = l & 15, lq = l >> 4;
  const int wm = wv >> 1, wn = wv & 1;  // wave-tile: rows wm*64.., cols wn*128..

  // staging: issue group covers 32 rows; thread t -> row (t>>3), 16B slot (t&7).
  // source pre-swizzle: logical slot = (t&7) ^ (row&7), LDS dest stays linear.
  const int srow = t >> 3;                              // 0..31
  const int koff = (((t & 7) ^ (srow & 7)) << 3);       // logical k-offset (shorts)
  const short* inS = (const short*)inp;
  const short* wS = (const short*)wpk;
  long abase[4];
#pragma unroll
  for (int i = 0; i < 4; i++) {
    int p = mtile * 128 + i * 32 + srow;
    int b = p / 25600; int r = p - b * 25600; int y = r / 160; int x = r - y * 160;
    abase[i] = (((long)b * 162 + y) * 162 + x) * 256 + koff;
  }
  const long bbase = ((long)srow) * 256 + koff;  // + j*8192 for row group j

  f32x4 acc[4][8];
#pragma unroll
  for (int i = 0; i < 4; i++)
#pragma unroll
    for (int j = 0; j < 8; j++) acc[i][j] = (f32x4){0.f, 0.f, 0.f, 0.f};

#pragma unroll 1
  for (int u = 0; u < 36; ++u) {
    const int tap = u >> 2, kc = u & 3;
    const int dy = tap / 3, dx = tap - dy * 3;
    const long aoff = ((long)(dy * 162 + dx)) * 256 + kc * 64;
    const long boff = (long)tap * 65536 + kc * 64;
    __syncthreads();  // previous step's LDS reads done
#pragma unroll
    for (int i = 0; i < 4; i++)
      async_ld16(inS + abase[i] + aoff, As + i * 2048 + t * 8);
#pragma unroll
    for (int j = 0; j < 8; j++)
      async_ld16(wS + bbase + boff + (long)j * 8192, Bs + j * 2048 + t * 8);
    __syncthreads();  // drains vmcnt(0): tiles ready
#pragma unroll
    for (int kk = 0; kk < 2; ++kk) {
      const int ps = (((kk << 2) | lq) ^ (lr & 7)) << 3;  // swizzled slot (shorts)
      s16x8 av[4], bv[8];
#pragma unroll
      for (int mi = 0; mi < 4; ++mi)
        av[mi] = *(const s16x8*)&As[(wm * 64 + mi * 16 + lr) * 64 + ps];
#pragma unroll
      for (int ni = 0; ni < 8; ++ni)
        bv[ni] = *(const s16x8*)&Bs[(wn * 128 + ni * 16 + lr) * 64 + ps];
      __builtin_amdgcn_s_setprio(1);
#pragma unroll
      for (int mi = 0; mi < 4; ++mi)
#pragma unroll
        for (int ni = 0; ni < 8; ++ni)
          acc[mi][ni] = __builtin_amdgcn_mfma_f32_16x16x32_bf16(av[mi], bv[ni], acc[mi][ni], 0, 0, 0);
      __builtin_amdgcn_s_setprio(0);
    }
  }

  // epilogue: y = relu(acc*alpha + beff) -> bf16, padded NHWC
  float al[8], be_[8];
#pragma unroll
  for (int ni = 0; ni < 8; ++ni) {
    int co = wn * 128 + ni * 16 + lr;
    al[ni] = alpha[co];
    be_[ni] = beff[co];
  }
#pragma unroll
  for (int mi = 0; mi < 4; ++mi) {
    int prow = mtile * 128 + wm * 64 + mi * 16 + lq * 4;
#pragma unroll
    for (int j = 0; j < 4; ++j) {
      int p = prow + j;
      int b = p / 25600; int r = p - b * 25600; int y = r / 160; int x = r - y * 160;
      long ob = (((long)b * 162 + (y + 1)) * 162 + (x + 1)) * 256 + wn * 128;
#pragma unroll
      for (int ni = 0; ni < 8; ++ni) {
        float v = acc[mi][ni][j] * al[ni] + be_[ni];
        outp[ob + ni * 16 + lr] = __float2bfloat16(fmaxf(v, 0.f));
      }
    }
  }
}

// ---------------- 5. cumsum along W: bf16 f -> fp32 S, channel-pair vectorized ----------------
__global__ __launch_bounds__(256) void cumsum_w(const __hip_bfloat16* __restrict__ f2,
                                                float* __restrict__ S) {
  int row = blockIdx.x * 2 + (threadIdx.x >> 7);   // 0..639
  int b = row / 160, y = row - (row / 160) * 160;
  int cp = threadIdx.x & 127;                      // channel pair index
  const unsigned* src =
      (const unsigned*)((const short*)f2 + (((size_t)b * 162 + y + 1) * 162 + 1) * 256) + cp;
  float2* dst = (float2*)(S + (((size_t)b * 161 + y + 1) * 161) * 256) + cp;
  dst[0] = float2{0.f, 0.f};
  float r0 = 0.f, r1 = 0.f;
  for (int x4 = 0; x4 < 160; x4 += 4) {
    unsigned v[4];
#pragma unroll
    for (int k = 0; k < 4; k++) v[k] = src[(size_t)(x4 + k) * 128];
#pragma unroll
    for (int k = 0; k < 4; k++) {
      r0 += __uint_as_float((v[k] & 0xffffu) << 16);
      r1 += __uint_as_float(v[k] & 0xffff0000u);
      dst[(size_t)(x4 + k + 1) * 128] = float2{r0, r1};
    }
  }
}

// ---------------- 6. cumsum along H in place ----------------
__global__ __launch_bounds__(256) void cumsum_h(float* __restrict__ S) {
  int bi = blockIdx.x;  // 4*161
  int b = bi / 161, q = bi - (bi / 161) * 161;
  int c = threadIdx.x;
  float* col = S + (((size_t)b * 161) * 161 + q) * 256 + c;
  const size_t ys = (size_t)161 * 256;
  col[0] = 0.f;
  float run = 0.f;
  for (int y0 = 1; y0 <= 160; y0 += 8) {
    float v[8];
#pragma unroll
    for (int k = 0; k < 8; k++) v[k] = col[(size_t)(y0 + k) * ys];
#pragma unroll
    for (int k = 0; k < 8; k++) { run += v[k]; col[(size_t)(y0 + k) * ys] = run; }
  }
}

// ---------------- 7. ROI adaptive 7x7 pool + global avg via integral image ----------------
__global__ __launch_bounds__(256) void roi_pool(const float* __restrict__ S,
                                                const float* __restrict__ bbox,
                                                float* __restrict__ pooled,
                                                int* __restrict__ valid) {
  int bn = blockIdx.x;  // 0..2047
  int b = bn >> 9;
  int c = threadIdx.x;
  float bx1 = bbox[bn * 4 + 0], by1 = bbox[bn * 4 + 1];
  float bx2 = bbox[bn * 4 + 2], by2 = bbox[bn * 4 + 3];
  int x1 = min(max((int)floorf(bx1 * 160.f), 0), 160);
  int y1 = min(max((int)floorf(by1 * 160.f), 0), 160);
  int x2 = min(max((int)floorf(bx2 * 160.f), 0), 160);
  int y2 = min(max((int)floorf(by2 * 160.f), 0), 160);
  int vld = (x2 > x1 && y2 > y1) ? 1 : 0;
  int hl = max(y2 - y1, 1), wl = max(x2 - x1, 1);
  int hs[7], he[7], ws_[7], we_[7];
  float rh[7], rw[7];
#pragma unroll
  for (int i = 0; i < 7; i++) {
    hs[i] = y1 + (i * hl) / 7;
    he[i] = y1 + ((i + 1) * hl + 6) / 7;
    rh[i] = 1.f / (float)(he[i] - hs[i]);
    ws_[i] = x1 + (i * wl) / 7;
    we_[i] = x1 + ((i + 1) * wl + 6) / 7;
    rw[i] = 1.f / (float)(we_[i] - ws_[i]);
  }
  const float* Sb = S + (size_t)b * 161 * 161 * 256 + c;
  float acc = 0.f;
#pragma unroll
  for (int i = 0; i < 7; i++) {
    const float* rE = Sb + (size_t)he[i] * (161 * 256);
    const float* rS = Sb + (size_t)hs[i] * (161 * 256);
#pragma unroll
    for (int j = 0; j < 7; j++) {
      size_t qe = (size_t)we_[j] * 256, qs = (size_t)ws_[j] * 256;
      float s = rE[qe] - rS[qe] - rE[qs] + rS[qs];
      acc += s * (rh[i] * rw[j]);
    }
  }
  pooled[(size_t)bn * 256 + c] = acc * (1.f / 49.f);
  if (c == 0) valid[bn] = vld;
}

// ---------------- 8. MLP (256->128 relu ->128) + mask + L2 normalize ----------------
__global__ __launch_bounds__(128) void mlp_norm(const float* __restrict__ pooled,
                                                const int* __restrict__ valid,
                                                const float* __restrict__ w1t,
                                                const float* __restrict__ b1,
                                                const float* __restrict__ w2t,
                                                const float* __restrict__ b2,
                                                float* __restrict__ out) {
  int bn = blockIdx.x;
  int t = threadIdx.x;
  __shared__ float pl[256];
  __shared__ float hh[128];
  __shared__ float red[2];
  pl[t] = pooled[(size_t)bn * 256 + t];
  pl[t + 128] = pooled[(size_t)bn * 256 + 128 + t];
  __syncthreads();
  float a = b1[t];
#pragma unroll 8
  for (int k = 0; k < 256; k++) a += w1t[k * 128 + t] * pl[k];
  hh[t] = fmaxf(a, 0.f);
  __syncthreads();
  float f = b2[t];
#pragma unroll 8
  for (int k = 0; k < 128; k++) f += w2t[k * 128 + t] * hh[k];
  if (!valid[bn]) f = 0.f;
  float ss = f * f;
#pragma unroll
  for (int off = 32; off > 0; off >>= 1) ss += __shfl_xor(ss, off);
  if ((t & 63) == 0) red[t >> 6] = ss;
  __syncthreads();
  float nrm = fmaxf(sqrtf(red[0] + red[1]), 1e-12f);
  out[(size_t)bn * 128 + t] = f / nrm;
}

// ---------------- launch ----------------
extern "C" void kernel_launch(void* const* d_in, const int* in_sizes, int n_in,
                              void* d_out, int out_size, void* d_ws, size_t ws_size,
                              hipStream_t stream) {
  const float* x = (const float*)d_in[0];
  const float* bboxes = (const float*)d_in[1];
  const float* conv_w = (const float*)d_in[2];
  const float* conv_b = (const float*)d_in[3];
  const float* bn_g = (const float*)d_in[4];
  const float* bn_b = (const float*)d_in[5];
  const float* bn_m = (const float*)d_in[6];
  const float* bn_v = (const float*)d_in[7];
  const float* w1 = (const float*)d_in[8];
  const float* b1 = (const float*)d_in[9];
  const float* w2 = (const float*)d_in[10];
  const float* b2 = (const float*)d_in[11];

  char* ws = (char*)d_ws;
  const size_t PADB = (size_t)4 * 162 * 162 * 256 * 2;   // 53,747,712 B
  const size_t WPKB = (size_t)2 * 9 * 256 * 256 * 2;     // 2,359,296 B
  const size_t SB = (size_t)4 * 161 * 161 * 256 * 4;     // 106,172,416 B
  const size_t PLB = (size_t)4 * 512 * 256 * 4;          // pooled 2 MB

  __hip_bfloat16* xpad = (__hip_bfloat16*)(ws);
  __hip_bfloat16* f1 = (__hip_bfloat16*)(ws + PADB);
  __hip_bfloat16* wpk = (__hip_bfloat16*)(ws + 2 * PADB);
  float* abuf = (float*)(ws + 2 * PADB + WPKB);
  float* S = (float*)(ws + 2 * PADB + WPKB + 4096);
  float* pooled = (float*)(ws + 2 * PADB + WPKB + 4096 + SB);
  int* valid = (int*)(ws + 2 * PADB + WPKB + 4096 + SB + PLB);
  float* w1t = (float*)(ws + 2 * PADB + WPKB + 4096 + SB + PLB + 8192);
  float* w2t = w1t + 32768;

  zero_borders<<<5152, 256, 0, stream>>>(xpad, f1);
  nchw2nhwc<<<25600, dim3(32, 8), 0, stream>>>(x, xpad);
  pack_w<<<4608, 256, 0, stream>>>(conv_w, wpk);
  prep_bn<<<2, 256, 0, stream>>>(conv_b, bn_g, bn_b, bn_m, bn_v, abuf);
  pack_mlp<<<192, 256, 0, stream>>>(w1, w2, w1t, w2t);

  conv_bn_relu<<<800, 256, 0, stream>>>(xpad, f1, wpk, abuf, abuf + 512);
  conv_bn_relu<<<800, 256, 0, stream>>>(f1, xpad, wpk + (size_t)9 * 256 * 256, abuf + 256, abuf + 768);

  cumsum_w<<<320, 256, 0, stream>>>(xpad, S);
  cumsum_h<<<644, 256, 0, stream>>>(S);
  roi_pool<<<2048, 256, 0, stream>>>(S, bboxes, pooled, valid);
  mlp_norm<<<2048, 128, 0, stream>>>(pooled, valid, w1t, b1, w2t, b2, (float*)d_out);
}